// Round 8
// baseline (328.311 us; speedup 1.0000x reference)
//
#include <hip/hip_runtime.h>

#define EPS_F 1e-7f

typedef float f4v __attribute__((ext_vector_type(4)));  // clang-native vec4
                                                        // (nt-store compatible)

constexpr int Bb = 8;
constexpr int Ss = 512;
constexpr int Ff = 128;
constexpr int TQ = 8;                 // queries per block
constexpr int OUTROW = Ff + Ff * Ff;  // 16512 floats per output row
constexpr int OUTROW4 = OUTROW / 4;   // 4128 float4 per output row

__global__ __launch_bounds__(256) void attn_fused(const float* __restrict__ x,
                                                  float* __restrict__ out) {
  const int t = threadIdx.x;          // 0..255
  const int bi = blockIdx.x;          // 0..511
  const int b = bi >> 6;              // 64 query-tiles per batch
  const int i0 = (bi & 63) * TQ;

  __shared__ float qt[TQ * Ff];         // 4 KB  query tile
  __shared__ float e[TQ][Ss];           // 16 KB exp(scores)
  __shared__ f4v ctx4[TQ][Ff / 4];      // 4 KB  context vectors
  __shared__ float inv_d[TQ];
  __shared__ float red[TQ][4];

  const float* xb = x + (size_t)b * Ss * Ff;

  // ---- load query tile (1024 floats = 256 float4, one per thread) ----
  {
    const f4v* src = (const f4v*)(xb + (size_t)i0 * Ff);
    ((f4v*)qt)[t] = src[t];
  }
  __syncthreads();

  // ---- phase 1: scores + exp + per-q partial sums ----
  // thread t handles key rows s = t and s = t+256 (contiguous per-row loads)
  float lsum[TQ];
#pragma unroll
  for (int q = 0; q < TQ; ++q) lsum[q] = 0.f;

  const f4v* q4 = (const f4v*)qt;
  for (int ss = 0; ss < 2; ++ss) {
    const int s = t + ss * 256;
    const f4v* row = (const f4v*)(xb + (size_t)s * Ff);
    float acc[TQ];
#pragma unroll
    for (int q = 0; q < TQ; ++q) acc[q] = 0.f;
#pragma unroll 4
    for (int k = 0; k < Ff / 4; ++k) {
      const f4v v = row[k];
#pragma unroll
      for (int q = 0; q < TQ; ++q) {
        const f4v qv = q4[q * (Ff / 4) + k];  // LDS broadcast
        acc[q] = fmaf(v.x, qv.x, acc[q]);
        acc[q] = fmaf(v.y, qv.y, acc[q]);
        acc[q] = fmaf(v.z, qv.z, acc[q]);
        acc[q] = fmaf(v.w, qv.w, acc[q]);
      }
    }
#pragma unroll
    for (int q = 0; q < TQ; ++q) {
      const float ex = expf(acc[q]);  // reference uses plain exp, no max-sub
      e[q][s] = ex;
      lsum[q] += ex;
    }
  }

  // ---- block reduction of denominators ----
#pragma unroll
  for (int q = 0; q < TQ; ++q) {
    float v = lsum[q];
#pragma unroll
    for (int off = 32; off > 0; off >>= 1) v += __shfl_down(v, off, 64);
    lsum[q] = v;  // lane 0 holds wave sum
  }
  const int lane = t & 63, wid = t >> 6;
  if (lane == 0) {
#pragma unroll
    for (int q = 0; q < TQ; ++q) red[q][wid] = lsum[q];
  }
  __syncthreads();
  if (t < TQ) {
    const float d = ((red[t][0] + red[t][1]) + red[t][2]) + red[t][3];
    inv_d[t] = 1.0f / (d + EPS_F);
  }
  __syncthreads();

  // ---- phase 2: ctx[q][f] = inv_d[q] * sum_s e[q][s] * x[b][s][f] ----
  // thread t -> (q = t>>5, f4 = t&31); coalesced 512B loads per s, L1-hot
  {
    const int f4 = t & 31;
    const int q = t >> 5;
    const f4v* xcol = (const f4v*)xb;
    const float* eq = e[q];
    f4v a = {0.f, 0.f, 0.f, 0.f};
#pragma unroll 4
    for (int s = 0; s < Ss; ++s) {
      const f4v v = xcol[s * 32 + f4];
      const float w = eq[s];
      a.x = fmaf(w, v.x, a.x);
      a.y = fmaf(w, v.y, a.y);
      a.z = fmaf(w, v.z, a.z);
      a.w = fmaf(w, v.w, a.w);
    }
    const float inv = inv_d[q];
    a.x *= inv; a.y *= inv; a.z *= inv; a.w *= inv;
    ctx4[q][f4] = a;
  }
  __syncthreads();

  // ---- phase 3: write out = concat([x_row, tile(ctx_row, F)]) ----
  // Output is write-only: use nontemporal stores so the 270 MB stream does
  // not evict the hot 256 KB/batch input rows from the per-XCD L2.
  f4v* out4 = (f4v*)out;
#pragma unroll
  for (int qq = 0; qq < TQ; ++qq) {
    const size_t rb4 = (size_t)(b * Ss + i0 + qq) * OUTROW4;
    if (t < 32) {
      __builtin_nontemporal_store(((const f4v*)qt)[qq * 32 + t],
                                  &out4[rb4 + t]);  // x part
    }
    const f4v cv = ctx4[qq][t & 31];
    f4v* dst = out4 + rb4 + 32;
#pragma unroll
    for (int k = 0; k < 16; ++k) {
      __builtin_nontemporal_store(cv, &dst[t + k * 256]);  // 1 KB/wave, coalesced
    }
  }
}

extern "C" void kernel_launch(void* const* d_in, const int* in_sizes, int n_in,
                              void* d_out, int out_size, void* d_ws, size_t ws_size,
                              hipStream_t stream) {
  const float* x = (const float*)d_in[0];
  float* out = (float*)d_out;
  attn_fused<<<dim3(Bb * (Ss / TQ)), dim3(256), 0, stream>>>(x, out);
}